// Round 3
// baseline (61107.239 us; speedup 1.0000x reference)
//
#include <hip/hip_runtime.h>
#include <hip/hip_bf16.h>
#include <hip/hip_cooperative_groups.h>

namespace cg = cooperative_groups;

// Problem constants
constexpr int M_ = 16, T_ = 512, D_ = 512, H_ = 512, QK_ = 256, G4_ = 2048;
constexpr float SCALE_ = 1.0f / 16.0f;   // 1/sqrt(QK)

// ---- workspace layout (float element offsets) ----  total ~25.3 MB
constexpr size_t KEY_OFF = 0;                   // key_x_all  [M][T][QK] f32 (8MB)
constexpr size_t VAL_OFF = 2097152;             // val1_all   [M][T][D]  f32 (16MB)
constexpr size_t H_OFF   = 6291456;             // h          [M][H]
constexpr size_t C_OFF   = H_OFF + 8192;        // c
constexpr size_t TH_OFF  = C_OFF + 8192;        // temp_h (active rows)
constexpr size_t K2_OFF  = TH_OFF + 8192;       // k2 cache [M][H]
constexpr size_t V2_OFF  = K2_OFF + 8192;       // v2 cache
constexpr size_t Q2_OFF  = V2_OFF + 8192;       // q2 per slot [4][H]
constexpr size_t L0_OFF  = Q2_OFF + 2048;       // logit0 partials [M][4]
constexpr size_t L1_OFF  = L0_OFF + 64;         // logit1 partials [M][4]

__device__ inline void load8f(const float* p, float f[8]) {
  float4 a = reinterpret_cast<const float4*>(p)[0];
  float4 b = reinterpret_cast<const float4*>(p)[1];
  f[0] = a.x; f[1] = a.y; f[2] = a.z; f[3] = a.w;
  f[4] = b.x; f[5] = b.y; f[6] = b.z; f[7] = b.w;
}

__device__ inline float waveReduce(float v) {
#pragma unroll
  for (int d = 32; d > 0; d >>= 1) v += __shfl_xor(v, d);
  return v;
}

__device__ inline float sigm(float x) { return 1.f / (1.f + expf(-x)); }

// ============================================================================
// Precompute: key_x_all = x @ Wk^T + bk ; val1_all = x @ Wv^T + bv
// tiled fp32 GEMM, tile 64(t) x 64(o), K-chunk 32. grid = 16 m * 8 tt * 12 ot
// ============================================================================
__global__ void __launch_bounds__(256) keyval_kernel(
    const float* __restrict__ x, const float* __restrict__ Wk,
    const float* __restrict__ Wv, const float* __restrict__ bk,
    const float* __restrict__ bv, float* __restrict__ wsf) {
  __shared__ float Xs[64][33];
  __shared__ float Ws[64][33];
  int bid = blockIdx.x, tid = threadIdx.x;
  int m = bid / 96, r = bid % 96;
  int tt = r / 12, ot = r % 12;
  const float* xb = x + ((size_t)m * T_ + tt * 64) * D_;
  const float* wb; const float* bias; float* dst; int ld;
  if (ot < 4) {
    wb = Wk + (size_t)m * QK_ * D_ + (size_t)(ot * 64) * D_;
    bias = bk + m * QK_ + ot * 64;
    dst = wsf + KEY_OFF + ((size_t)m * T_ + tt * 64) * QK_ + ot * 64;
    ld = QK_;
  } else {
    wb = Wv + (size_t)m * D_ * D_ + (size_t)((ot - 4) * 64) * D_;
    bias = bv + m * D_ + (ot - 4) * 64;
    dst = wsf + VAL_OFF + ((size_t)m * T_ + tt * 64) * D_ + (ot - 4) * 64;
    ld = D_;
  }
  int lr = tid >> 2, lc = (tid & 3) * 8;
  int tx = tid & 15, ty = tid >> 4;
  float acc[4][4] = {};
  for (int k0 = 0; k0 < D_; k0 += 32) {
    float tmp[8];
    load8f(xb + (size_t)lr * D_ + k0 + lc, tmp);
#pragma unroll
    for (int i = 0; i < 8; ++i) Xs[lr][lc + i] = tmp[i];
    load8f(wb + (size_t)lr * D_ + k0 + lc, tmp);
#pragma unroll
    for (int i = 0; i < 8; ++i) Ws[lr][lc + i] = tmp[i];
    __syncthreads();
#pragma unroll
    for (int kk = 0; kk < 32; ++kk) {
      float xa[4], wv4[4];
#pragma unroll
      for (int a = 0; a < 4; ++a) xa[a] = Xs[ty * 4 + a][kk];
#pragma unroll
      for (int b = 0; b < 4; ++b) wv4[b] = Ws[tx * 4 + b][kk];
#pragma unroll
      for (int a = 0; a < 4; ++a)
#pragma unroll
        for (int b = 0; b < 4; ++b) acc[a][b] += xa[a] * wv4[b];
    }
    __syncthreads();
  }
#pragma unroll
  for (int b = 0; b < 4; ++b) {
    float bias_v = bias[tx * 4 + b];
#pragma unroll
    for (int a = 0; a < 4; ++a)
      dst[(size_t)(ty * 4 + a) * ld + tx * 4 + b] = acc[a][b] + bias_v;
  }
}

// ============================================================================
// Main sequential kernel (cooperative). 256 WGs x 256 threads, 3 grid syncs
// per time step:
//   A: finalize step t-1 (att2 16x16 epilogue, redundant in WGs 0..63) +
//      write out[t-1]/h; compute q & logit partials for step t
//   C: redundant top-k; gates+LSTM cell for the 4 active rows -> temp_h
//   D: q2/k2/v2 matvecs ([h][o] layout, lane-per-column, coalesced);
//      zero c of inactive rows
// ============================================================================
__global__ void __launch_bounds__(256) rim_main(
    const float* __restrict__ Wq, const float* __restrict__ bq,
    const float* __restrict__ bk, const float* __restrict__ bv,
    const float* __restrict__ Wih, const float* __restrict__ bih,
    const float* __restrict__ Whh, const float* __restrict__ bhh,
    const float* __restrict__ Wqg, const float* __restrict__ Wkg,
    const float* __restrict__ Wvg,
    float* __restrict__ wsf, float* __restrict__ out0, float* __restrict__ out1) {
  cg::grid_group grid = cg::this_grid();
  const int wg = blockIdx.x, tid = threadIdx.x;
  const int lane = tid & 63, wv = tid >> 6;

  float* keyA = wsf + KEY_OFF;
  float* valA = wsf + VAL_OFF;
  float* hB = wsf + H_OFF;
  float* cB = wsf + C_OFF;
  float* thB = wsf + TH_OFF;
  float* k2B = wsf + K2_OFF;
  float* v2B = wsf + V2_OFF;
  float* q2B = wsf + Q2_OFF;
  float* l0B = wsf + L0_OFF;
  float* l1B = wsf + L1_OFF;

  __shared__ float s_newh[4][512];
  __shared__ float s_sel[512];
  __shared__ float s_vec[512];
  __shared__ float s_dv[512];
  __shared__ float s_part[256];
  __shared__ float s_small[64];
  __shared__ float s_w2[64];
  __shared__ float s_red[8];
  __shared__ float s_gv[4][8];

  // ws is poisoned each call: zero-init state
  if (wg < 16) {
    for (int i = tid; i < 512; i += 256) {
      hB[wg * 512 + i] = 0.f;
      cB[wg * 512 + i] = 0.f;
    }
  }
  grid.sync();

  int p0 = 0, p1 = 0, p2 = 0, p3 = 0;  // active rows of step t-1
  int r0 = 0, r1 = 0, r2 = 0, r3 = 0;  // active rows of step t

  for (int t = 0; t <= T_; ++t) {
    // ================= Phase A =================
    if (t > 0 && wg < 64) {
      // --- att2/inter/new_h finalization of step t-1 (redundant per WG) ---
      {
        int s_ = tid >> 6, j_ = (tid >> 2) & 15, pp = tid & 3;
        const float* q2 = q2B + s_ * 512 + pp * 128;
        const float* k2 = k2B + j_ * 512 + pp * 128;
        float part = 0.f;
#pragma unroll 8
        for (int i = 0; i < 128; i += 4)
          part += q2[i] * k2[i] + q2[i + 1] * k2[i + 1] + q2[i + 2] * k2[i + 2] +
                  q2[i + 3] * k2[i + 3];
        part += __shfl_xor(part, 1);
        part += __shfl_xor(part, 2);
        if (pp == 0) s_small[s_ * 16 + j_] = part;
      }
      __syncthreads();
      if (tid < 4) {  // row softmax (np-style: max-subtract)
        float mx = -1e30f;
        for (int j = 0; j < 16; ++j) mx = fmaxf(mx, s_small[tid * 16 + j]);
        float sm = 0.f;
        for (int j = 0; j < 16; ++j) {
          float e = expf(s_small[tid * 16 + j] - mx);
          s_w2[tid * 16 + j] = e; sm += e;
        }
        float inv = 1.f / sm;
        for (int j = 0; j < 16; ++j) s_w2[tid * 16 + j] *= inv;
      }
      __syncthreads();
      {
        int s_ = tid >> 6, o0 = (tid & 63) * 8;
        int myrow = s_ == 0 ? p0 : s_ == 1 ? p1 : s_ == 2 ? p2 : p3;
        float acc8[8] = {};
#pragma unroll
        for (int j = 0; j < 16; ++j) {
          float w = s_w2[s_ * 16 + j];
          const float4* v2 = reinterpret_cast<const float4*>(v2B + j * 512 + o0);
          float4 a = v2[0], b = v2[1];
          acc8[0] += w * a.x; acc8[1] += w * a.y; acc8[2] += w * a.z; acc8[3] += w * a.w;
          acc8[4] += w * b.x; acc8[5] += w * b.y; acc8[6] += w * b.z; acc8[7] += w * b.w;
        }
        const float* th = thB + (size_t)myrow * 512 + o0;
#pragma unroll
        for (int i = 0; i < 8; ++i) s_newh[s_][o0 + i] = acc8[i] + th[i];
      }
      __syncthreads();
      // writers: out[t-1] all rows; h update for prev-active rows
      if (wg < 16) {
        int m = wg;
        int slot = (m == p0) ? 0 : (m == p1) ? 1 : (m == p2) ? 2 : (m == p3) ? 3 : -1;
        for (int i = tid; i < 512; i += 256) {
          float v = (slot >= 0) ? s_newh[slot][i] : hB[m * 512 + i];
          out0[(size_t)(t - 1) * (M_ * H_) + m * 512 + i] = v;
          if (slot >= 0) hB[m * 512 + i] = v;
        }
      }
    }
    if (t == T_) break;

    // --- A1: q = h@Wq^T + bq and logit partials (tasks: 16 m x 4 chunks) ---
    if (wg < 64) {
      int m = wg >> 2, kc = wg & 3;
      int slot = -1;
      if (t > 0) slot = (m == p0) ? 0 : (m == p1) ? 1 : (m == p2) ? 2 : (m == p3) ? 3 : -1;
      float hreg[8];
      if (slot >= 0) {
#pragma unroll
        for (int i = 0; i < 8; ++i) hreg[i] = s_newh[slot][lane * 8 + i];
      } else {
        load8f(hB + m * 512 + lane * 8, hreg);
      }
      float l1p = 0.f, l0p = 0.f;
      for (int oi = 0; oi < 16; ++oi) {
        int o = kc * 64 + wv * 16 + oi;
        float w8[8];
        load8f(Wq + ((size_t)m * QK_ + o) * H_ + lane * 8, w8);
        float acc = 0.f;
#pragma unroll
        for (int i = 0; i < 8; ++i) acc += hreg[i] * w8[i];
        acc = waveReduce(acc);
        if (lane == 0) {
          float q = acc + bq[m * QK_ + o];
          l1p += q * keyA[((size_t)m * T_ + t) * QK_ + o];
          l0p += q * bk[m * QK_ + o];
        }
      }
      if (lane == 0) { s_red[wv] = l1p; s_red[4 + wv] = l0p; }
      __syncthreads();
      if (tid == 0) {  // deterministic fixed-order partial write
        l1B[m * 4 + kc] = s_red[0] + s_red[1] + s_red[2] + s_red[3];
        l0B[m * 4 + kc] = s_red[4] + s_red[5] + s_red[6] + s_red[7];
      }
    }
    grid.sync();

    // ================= Phase C =================
    if (tid < 16) {
      float l0 = (l0B[tid * 4] + l0B[tid * 4 + 1] + l0B[tid * 4 + 2] + l0B[tid * 4 + 3]) * SCALE_;
      float l1 = (l1B[tid * 4] + l1B[tid * 4 + 1] + l1B[tid * 4 + 2] + l1B[tid * 4 + 3]) * SCALE_;
      float mx = fmaxf(l0, l1);
      float e0 = expf(l0 - mx), e1 = expf(l1 - mx);
      float inv = 1.f / (e0 + e1);
      s_small[tid] = e0 * inv;        // att0
      s_small[16 + tid] = e1 * inv;   // att1
    }
    __syncthreads();
    {
      // top_k(-att0, 4): 4 smallest att0, ties -> smaller index (strict >)
      unsigned chosen = 0;
      int rr[4];
#pragma unroll
      for (int s = 0; s < 4; ++s) {
        float best = -2.f; int bm = 0;
        for (int mm = 0; mm < 16; ++mm) {
          if (chosen & (1u << mm)) continue;
          float v = -s_small[mm];
          if (v > best) { best = v; bm = mm; }
        }
        rr[s] = bm; chosen |= 1u << bm;
      }
      r0 = rr[0]; r1 = rr[1]; r2 = rr[2]; r3 = rr[3];
    }
    if (wg == 0 && tid < 4) {
      int rowv = tid == 0 ? r0 : tid == 1 ? r1 : tid == 2 ? r2 : r3;
      out1[(size_t)t * 4 + tid] = (float)rowv;
    }
    // --- C1: gates + LSTM cell for active rows (tasks: 4 slots x 64 j-chunks) ---
    {
      int s_ = wg >> 6, jc = wg & 63, j0 = jc * 8;
      int m = s_ == 0 ? r0 : s_ == 1 ? r1 : s_ == 2 ? r2 : r3;
      float a0v = s_small[m], a1v = s_small[16 + m];
      for (int i = tid; i < 512; i += 256) {
        s_sel[i] = a0v * bv[m * 512 + i] + a1v * valA[((size_t)m * T_ + t) * D_ + i];
        s_vec[i] = hB[m * 512 + i];
      }
      __syncthreads();
      float selreg[8], hreg[8];
#pragma unroll
      for (int i = 0; i < 8; ++i) { selreg[i] = s_sel[lane * 8 + i]; hreg[i] = s_vec[lane * 8 + i]; }
#pragma unroll
      for (int i = 0; i < 8; ++i) {
        int g = wv * 512 + j0 + i;  // wave -> gate type (i,f,g,o)
        float w1[8], w2[8];
        load8f(Wih + ((size_t)m * G4_ + g) * D_ + lane * 8, w1);
        load8f(Whh + ((size_t)m * G4_ + g) * H_ + lane * 8, w2);
        float acc = 0.f;
#pragma unroll
        for (int k = 0; k < 8; ++k) acc += selreg[k] * w1[k] + hreg[k] * w2[k];
        acc = waveReduce(acc);
        if (lane == 0)
          s_gv[wv][i] = acc + bih[m * G4_ + g] + bhh[m * G4_ + g];
      }
      __syncthreads();
      if (tid < 8) {
        float gi = s_gv[0][tid], gf = s_gv[1][tid], gg = s_gv[2][tid], go = s_gv[3][tid];
        int j = j0 + tid;
        float cold = cB[m * 512 + j];
        float cn = sigm(gf) * cold + sigm(gi) * tanhf(gg);
        float hn = sigm(go) * tanhf(cn);
        cB[m * 512 + j] = cn;     // new_c (active rows)
        thB[m * 512 + j] = hn;    // temp_h (active rows)
      }
    }
    grid.sync();

    // ================= Phase D =================
    // tasks 0..287: 36 matvecs (16 k2 + 16 v2 + 4 q2) x 8 column-chunks of 64.
    // Weights in ORIGINAL [h][o] layout: lane owns column o, loop over h with
    // src[h] broadcast from LDS; 4 waves split h 128-each, fixed-order combine.
    // tasks 288..303: zero c of inactive rows.
    {
      unsigned amask = (1u << r0) | (1u << r1) | (1u << r2) | (1u << r3);
      for (int task = wg; task < 304; task += 256) {
        if (task < 288) {
          int mv = task >> 3, oc = task & 7;
          const float* wt; const float* src; float* dst;
          if (mv < 16) {
            int row = mv;
            wt = Wkg + (size_t)row * H_ * H_;
            src = ((amask >> row) & 1) ? (thB + row * 512) : (hB + row * 512);
            dst = k2B + row * 512;
          } else if (mv < 32) {
            int row = mv - 16;
            wt = Wvg + (size_t)row * H_ * H_;
            src = ((amask >> row) & 1) ? (thB + row * 512) : (hB + row * 512);
            dst = v2B + row * 512;
          } else {
            int s2 = mv - 32;
            int row = s2 == 0 ? r0 : s2 == 1 ? r1 : s2 == 2 ? r2 : r3;
            wt = Wqg + (size_t)row * H_ * H_;
            src = thB + row * 512;
            dst = q2B + s2 * 512;
          }
          for (int i = tid; i < 512; i += 256) s_dv[i] = src[i];
          __syncthreads();
          const float* wp = wt + (size_t)(wv * 128) * H_ + oc * 64 + lane;
          float acc = 0.f;
#pragma unroll 8
          for (int hh = 0; hh < 128; ++hh)
            acc += s_dv[wv * 128 + hh] * wp[(size_t)hh * H_];
          s_part[wv * 64 + lane] = acc;
          __syncthreads();
          if (tid < 64)
            dst[oc * 64 + tid] = (s_part[tid] + s_part[64 + tid]) +
                                 (s_part[128 + tid] + s_part[192 + tid]);
          __syncthreads();  // protect s_dv/s_part before next task iteration
        } else {
          int rI = task - 288;  // zero c of inactive rows (new_c = m*c_new)
          if (!((amask >> rI) & 1))
            for (int i = tid; i < 512; i += 256) cB[rI * 512 + i] = 0.f;
        }
      }
    }
    p0 = r0; p1 = r1; p2 = r2; p3 = r3;
    grid.sync();
  }
}

// ============================================================================
extern "C" void kernel_launch(void* const* d_in, const int* in_sizes, int n_in,
                              void* d_out, int out_size, void* d_ws, size_t ws_size,
                              hipStream_t stream) {
  const float* x   = (const float*)d_in[0];
  const float* Wq  = (const float*)d_in[1];
  const float* bq  = (const float*)d_in[2];
  const float* Wk  = (const float*)d_in[3];
  const float* bk  = (const float*)d_in[4];
  const float* Wv  = (const float*)d_in[5];
  const float* bv  = (const float*)d_in[6];
  const float* Wih = (const float*)d_in[7];
  const float* bih = (const float*)d_in[8];
  const float* Whh = (const float*)d_in[9];
  const float* bhh = (const float*)d_in[10];
  const float* Wqg = (const float*)d_in[11];
  const float* Wkg = (const float*)d_in[12];
  const float* Wvg = (const float*)d_in[13];
  float* wsf = (float*)d_ws;
  float* out0 = (float*)d_out;
  float* out1 = out0 + (size_t)T_ * M_ * H_;

  hipLaunchKernelGGL(keyval_kernel, dim3(1536), dim3(256), 0, stream,
                     x, Wk, Wv, bk, bv, wsf);

  void* kargs[] = {(void*)&Wq, (void*)&bq, (void*)&bk, (void*)&bv,
                   (void*)&Wih, (void*)&bih, (void*)&Whh, (void*)&bhh,
                   (void*)&Wqg, (void*)&Wkg, (void*)&Wvg,
                   (void*)&wsf, (void*)&out0, (void*)&out1};
  hipLaunchCooperativeKernel((void*)rim_main, dim3(256), dim3(256), kargs, 0,
                             stream);
}

// Round 4
// 59466.461 us; speedup vs baseline: 1.0276x; 1.0276x over previous
//
#include <hip/hip_runtime.h>
#include <hip/hip_bf16.h>
#include <hip/hip_cooperative_groups.h>

namespace cg = cooperative_groups;

// Problem constants
constexpr int M_ = 16, T_ = 512, D_ = 512, H_ = 512, QK_ = 256, G4_ = 2048;
constexpr float SCALE_ = 1.0f / 16.0f;   // 1/sqrt(QK)

// ---- workspace layout (float element offsets) ----  total ~25.3 MB
constexpr size_t KEY_OFF = 0;                   // key_x_all  [M][T][QK] f32 (8MB)
constexpr size_t VAL_OFF = 2097152;             // val1_all   [M][T][D]  f32 (16MB)
constexpr size_t H_OFF   = 6291456;             // h          [M][H]
constexpr size_t C_OFF   = H_OFF + 8192;        // c
constexpr size_t TH_OFF  = C_OFF + 8192;        // temp_h (active rows)
constexpr size_t K2_OFF  = TH_OFF + 8192;       // k2 cache [M][H]
constexpr size_t V2_OFF  = K2_OFF + 8192;       // v2 cache
constexpr size_t Q2_OFF  = V2_OFF + 8192;       // q2 per slot [4][H]
constexpr size_t L0_OFF  = Q2_OFF + 2048;       // logit0 partials [M][16]
constexpr size_t L1_OFF  = L0_OFF + 256;        // logit1 partials [M][16]

__device__ inline void load8f(const float* p, float f[8]) {
  float4 a = reinterpret_cast<const float4*>(p)[0];
  float4 b = reinterpret_cast<const float4*>(p)[1];
  f[0] = a.x; f[1] = a.y; f[2] = a.z; f[3] = a.w;
  f[4] = b.x; f[5] = b.y; f[6] = b.z; f[7] = b.w;
}

__device__ inline float waveReduce(float v) {
#pragma unroll
  for (int d = 32; d > 0; d >>= 1) v += __shfl_xor(v, d);
  return v;
}

__device__ inline float sigm(float x) { return 1.f / (1.f + expf(-x)); }

// ============================================================================
// Precompute: key_x_all = x @ Wk^T + bk ; val1_all = x @ Wv^T + bv
// ============================================================================
__global__ void __launch_bounds__(256) keyval_kernel(
    const float* __restrict__ x, const float* __restrict__ Wk,
    const float* __restrict__ Wv, const float* __restrict__ bk,
    const float* __restrict__ bv, float* __restrict__ wsf) {
  __shared__ float Xs[64][33];
  __shared__ float Ws[64][33];
  int bid = blockIdx.x, tid = threadIdx.x;
  int m = bid / 96, r = bid % 96;
  int tt = r / 12, ot = r % 12;
  const float* xb = x + ((size_t)m * T_ + tt * 64) * D_;
  const float* wb; const float* bias; float* dst; int ld;
  if (ot < 4) {
    wb = Wk + (size_t)m * QK_ * D_ + (size_t)(ot * 64) * D_;
    bias = bk + m * QK_ + ot * 64;
    dst = wsf + KEY_OFF + ((size_t)m * T_ + tt * 64) * QK_ + ot * 64;
    ld = QK_;
  } else {
    wb = Wv + (size_t)m * D_ * D_ + (size_t)((ot - 4) * 64) * D_;
    bias = bv + m * D_ + (ot - 4) * 64;
    dst = wsf + VAL_OFF + ((size_t)m * T_ + tt * 64) * D_ + (ot - 4) * 64;
    ld = D_;
  }
  int lr = tid >> 2, lc = (tid & 3) * 8;
  int tx = tid & 15, ty = tid >> 4;
  float acc[4][4] = {};
  for (int k0 = 0; k0 < D_; k0 += 32) {
    float tmp[8];
    load8f(xb + (size_t)lr * D_ + k0 + lc, tmp);
#pragma unroll
    for (int i = 0; i < 8; ++i) Xs[lr][lc + i] = tmp[i];
    load8f(wb + (size_t)lr * D_ + k0 + lc, tmp);
#pragma unroll
    for (int i = 0; i < 8; ++i) Ws[lr][lc + i] = tmp[i];
    __syncthreads();
#pragma unroll
    for (int kk = 0; kk < 32; ++kk) {
      float xa[4], wv4[4];
#pragma unroll
      for (int a = 0; a < 4; ++a) xa[a] = Xs[ty * 4 + a][kk];
#pragma unroll
      for (int b = 0; b < 4; ++b) wv4[b] = Ws[tx * 4 + b][kk];
#pragma unroll
      for (int a = 0; a < 4; ++a)
#pragma unroll
        for (int b = 0; b < 4; ++b) acc[a][b] += xa[a] * wv4[b];
    }
    __syncthreads();
  }
#pragma unroll
  for (int b = 0; b < 4; ++b) {
    float bias_v = bias[tx * 4 + b];
#pragma unroll
    for (int a = 0; a < 4; ++a)
      dst[(size_t)(ty * 4 + a) * ld + tx * 4 + b] = acc[a][b] + bias_v;
  }
}

// ============================================================================
// Main sequential kernel. 256 WGs x 1024 threads (16 waves/CU), 3 grid syncs
// per step. All phases use all waves with deep load ILP.
// ============================================================================
__global__ void __launch_bounds__(1024, 4) rim_main(
    const float* __restrict__ Wq, const float* __restrict__ bq,
    const float* __restrict__ bk, const float* __restrict__ bv,
    const float* __restrict__ Wih, const float* __restrict__ bih,
    const float* __restrict__ Whh, const float* __restrict__ bhh,
    const float* __restrict__ Wqg, const float* __restrict__ Wkg,
    const float* __restrict__ Wvg,
    float* __restrict__ wsf, float* __restrict__ out0, float* __restrict__ out1) {
  cg::grid_group grid = cg::this_grid();
  const int wg = blockIdx.x, tid = threadIdx.x;
  const int lane = tid & 63, wv = tid >> 6;

  float* keyA = wsf + KEY_OFF;
  float* valA = wsf + VAL_OFF;
  float* hB = wsf + H_OFF;
  float* cB = wsf + C_OFF;
  float* thB = wsf + TH_OFF;
  float* k2B = wsf + K2_OFF;
  float* v2B = wsf + V2_OFF;
  float* q2B = wsf + Q2_OFF;
  float* l0B = wsf + L0_OFF;
  float* l1B = wsf + L1_OFF;

  __shared__ float s_newh[4][512];   // 8 KB
  __shared__ float s_sel[512];       // 2 KB
  __shared__ float s_hact[512];      // 2 KB
  __shared__ float s_dv[512];        // 2 KB
  __shared__ float4 s_pd[1024];      // 16 KB
  __shared__ float s_small[64];
  __shared__ float s_w2[64];
  __shared__ float s_redA[16];
  __shared__ float s_redB[16];
  __shared__ float s_gv[4][8];

  // ws is poisoned each call: zero-init state
  if (wg < 16 && tid < 512) {
    hB[wg * 512 + tid] = 0.f;
    cB[wg * 512 + tid] = 0.f;
  }
  grid.sync();

  int p0 = 0, p1 = 0, p2 = 0, p3 = 0;  // active rows of step t-1
  int r0 = 0, r1 = 0, r2 = 0, r3 = 0;  // active rows of step t

  for (int t = 0; t <= T_; ++t) {
    // ================= Phase A: epilogue of step t-1 (all WGs, redundant) ===
    if (t > 0) {
      // scores: 64 (s,j) pairs x 8 threads each (64-float chunks)
      if (tid < 512) {
        int pr = tid >> 3, part = tid & 7;
        int s_ = pr >> 4, j_ = pr & 15;
        const float4* q4 = reinterpret_cast<const float4*>(q2B + s_ * 512 + part * 64);
        const float4* k4 = reinterpret_cast<const float4*>(k2B + j_ * 512 + part * 64);
        float acc = 0.f;
#pragma unroll
        for (int i = 0; i < 16; ++i) {
          float4 a = q4[i], b = k4[i];
          acc += a.x * b.x + a.y * b.y + a.z * b.z + a.w * b.w;
        }
        acc += __shfl_xor(acc, 1);
        acc += __shfl_xor(acc, 2);
        acc += __shfl_xor(acc, 4);
        if (part == 0) s_small[pr] = acc;
      }
      __syncthreads();
      if (tid < 4) {  // row softmax (max-subtract)
        float mx = -1e30f;
        for (int j = 0; j < 16; ++j) mx = fmaxf(mx, s_small[tid * 16 + j]);
        float sm = 0.f;
        for (int j = 0; j < 16; ++j) {
          float e = expf(s_small[tid * 16 + j] - mx);
          s_w2[tid * 16 + j] = e; sm += e;
        }
        float inv = 1.f / sm;
        for (int j = 0; j < 16; ++j) s_w2[tid * 16 + j] *= inv;
      }
      __syncthreads();
      {  // inter + new_h: 1024 threads x 2 outputs
        int s_ = tid >> 8, o0 = (tid & 255) * 2;
        float ax = 0.f, ay = 0.f;
#pragma unroll
        for (int j = 0; j < 16; ++j) {
          float w = s_w2[s_ * 16 + j];
          float2 v = *reinterpret_cast<const float2*>(v2B + j * 512 + o0);
          ax += w * v.x; ay += w * v.y;
        }
        int myrow = s_ == 0 ? p0 : s_ == 1 ? p1 : s_ == 2 ? p2 : p3;
        const float2 th = *reinterpret_cast<const float2*>(thB + (size_t)myrow * 512 + o0);
        s_newh[s_][o0] = ax + th.x;
        s_newh[s_][o0 + 1] = ay + th.y;
      }
      __syncthreads();
      // writers: out[t-1] all rows; h update for prev-active rows
      if (wg < 16 && tid < 512) {
        int m = wg;
        int slot = (m == p0) ? 0 : (m == p1) ? 1 : (m == p2) ? 2 : (m == p3) ? 3 : -1;
        float v = (slot >= 0) ? s_newh[slot][tid] : hB[m * 512 + tid];
        out0[(size_t)(t - 1) * (M_ * H_) + m * 512 + tid] = v;
        if (slot >= 0) hB[m * 512 + tid] = v;
      }
    }
    if (t == T_) break;

    // --- A1: q = h@Wq^T + bq, logit partials. WG=(m,oc); wave=1 output o. ---
    {
      int m = wg >> 4, oc = wg & 15;
      int slot = -1;
      if (t > 0) slot = (m == p0) ? 0 : (m == p1) ? 1 : (m == p2) ? 2 : (m == p3) ? 3 : -1;
      float hreg[8];
      if (slot >= 0) {
#pragma unroll
        for (int i = 0; i < 8; ++i) hreg[i] = s_newh[slot][lane * 8 + i];
      } else {
        load8f(hB + m * 512 + lane * 8, hreg);
      }
      int o = oc * 16 + wv;
      float w8[8];
      load8f(Wq + ((size_t)m * QK_ + o) * H_ + lane * 8, w8);
      float acc = 0.f;
#pragma unroll
      for (int i = 0; i < 8; ++i) acc += hreg[i] * w8[i];
      acc = waveReduce(acc);
      if (lane == 0) {
        float q = acc + bq[m * QK_ + o];
        s_redA[wv] = q * keyA[((size_t)m * T_ + t) * QK_ + o];
        s_redB[wv] = q * bk[m * QK_ + o];
      }
      __syncthreads();
      if (tid == 0) {  // deterministic fixed-order partial
        float a = 0.f, b = 0.f;
        for (int w = 0; w < 16; ++w) { a += s_redA[w]; b += s_redB[w]; }
        l1B[m * 16 + oc] = a;
        l0B[m * 16 + oc] = b;
      }
    }
    grid.sync();

    // ================= Phase C =================
    if (tid < 16) {
      float l0 = 0.f, l1 = 0.f;
      for (int i = 0; i < 16; ++i) { l0 += l0B[tid * 16 + i]; l1 += l1B[tid * 16 + i]; }
      l0 *= SCALE_; l1 *= SCALE_;
      float mx = fmaxf(l0, l1);
      float e0 = expf(l0 - mx), e1 = expf(l1 - mx);
      float inv = 1.f / (e0 + e1);
      s_small[tid] = e0 * inv;        // att0
      s_small[16 + tid] = e1 * inv;   // att1
    }
    __syncthreads();
    {  // top_k(-att0, 4): 4 smallest att0, ties -> smaller index
      unsigned chosen = 0;
      int rr[4];
#pragma unroll
      for (int s = 0; s < 4; ++s) {
        float best = -2.f; int bm = 0;
        for (int mm = 0; mm < 16; ++mm) {
          if (chosen & (1u << mm)) continue;
          float v = -s_small[mm];
          if (v > best) { best = v; bm = mm; }
        }
        rr[s] = bm; chosen |= 1u << bm;
      }
      r0 = rr[0]; r1 = rr[1]; r2 = rr[2]; r3 = rr[3];
    }
    if (wg == 0 && tid < 4) {
      int rowv = tid == 0 ? r0 : tid == 1 ? r1 : tid == 2 ? r2 : r3;
      out1[(size_t)t * 4 + tid] = (float)rowv;
    }
    // --- C1: gates + LSTM cell. WG=(slot, j-chunk of 8); wave = 2 gates. ---
    {
      int slot_c = wg >> 6, jc = wg & 63, j0 = jc * 8;
      int m = slot_c == 0 ? r0 : slot_c == 1 ? r1 : slot_c == 2 ? r2 : r3;
      float a0v = s_small[m], a1v = s_small[16 + m];
      if (tid < 512) {
        s_sel[tid] = a0v * bv[m * 512 + tid] + a1v * valA[((size_t)m * T_ + t) * D_ + tid];
        s_hact[tid] = hB[m * 512 + tid];
      }
      __syncthreads();
      float selreg[8], hreg[8];
#pragma unroll
      for (int i = 0; i < 8; ++i) { selreg[i] = s_sel[lane * 8 + i]; hreg[i] = s_hact[lane * 8 + i]; }
#pragma unroll
      for (int u = 0; u < 2; ++u) {
        int gl = wv * 2 + u;            // 0..31
        int type = gl >> 3, jj = gl & 7;
        int g = type * 512 + j0 + jj;
        float w1[8], w2[8];
        load8f(Wih + ((size_t)m * G4_ + g) * D_ + lane * 8, w1);
        load8f(Whh + ((size_t)m * G4_ + g) * H_ + lane * 8, w2);
        float acc = 0.f;
#pragma unroll
        for (int k = 0; k < 8; ++k) acc += selreg[k] * w1[k] + hreg[k] * w2[k];
        acc = waveReduce(acc);
        if (lane == 0)
          s_gv[type][jj] = acc + bih[m * G4_ + g] + bhh[m * G4_ + g];
      }
      __syncthreads();
      if (tid < 8) {
        float gi = s_gv[0][tid], gf = s_gv[1][tid], gg = s_gv[2][tid], go = s_gv[3][tid];
        int j = j0 + tid;
        float cold = cB[m * 512 + j];
        float cn = sigm(gf) * cold + sigm(gi) * tanhf(gg);
        float hn = sigm(go) * tanhf(cn);
        cB[m * 512 + j] = cn;     // new_c (active rows)
        thB[m * 512 + j] = hn;    // temp_h (active rows)
      }
    }
    grid.sync();

    // ================= Phase D =================
    // WGs 0..143: 36 matvecs x 4 o-chunks of 128. Thread=(og,hs):
    //   og=tid&31 -> 4 consecutive outputs (float4 weight loads, half-wave
    //   contiguous 512B); hs=tid>>5 -> 16-h strip. LDS fixed-order reduce.
    // WGs 144..159: zero c of inactive rows.
    {
      unsigned amask = (1u << r0) | (1u << r1) | (1u << r2) | (1u << r3);
      if (wg < 144) {
        int mv = wg >> 2, oq = wg & 3;
        const float* wt; const float* src; float* dst;
        if (mv < 16) {
          int row = mv;
          wt = Wkg + (size_t)row * H_ * H_;
          src = ((amask >> row) & 1) ? (thB + row * 512) : (hB + row * 512);
          dst = k2B + row * 512;
        } else if (mv < 32) {
          int row = mv - 16;
          wt = Wvg + (size_t)row * H_ * H_;
          src = ((amask >> row) & 1) ? (thB + row * 512) : (hB + row * 512);
          dst = v2B + row * 512;
        } else {
          int s2 = mv - 32;
          int row = s2 == 0 ? r0 : s2 == 1 ? r1 : s2 == 2 ? r2 : r3;
          wt = Wqg + (size_t)row * H_ * H_;
          src = thB + row * 512;
          dst = q2B + s2 * 512;
        }
        if (tid < 512) s_dv[tid] = src[tid];
        __syncthreads();
        int og = tid & 31, hs = tid >> 5;
        int o4 = oq * 128 + og * 4;
        const float4* wp = reinterpret_cast<const float4*>(wt + (size_t)(hs * 16) * H_ + o4);
        float4 a = {0.f, 0.f, 0.f, 0.f};
#pragma unroll
        for (int i = 0; i < 16; ++i) {
          float s = s_dv[hs * 16 + i];
          float4 w = wp[(size_t)i * 128];   // next h row: H_ floats = 128 float4
          a.x += s * w.x; a.y += s * w.y; a.z += s * w.z; a.w += s * w.w;
        }
        s_pd[hs * 32 + og] = a;
        __syncthreads();
        if (tid < 32) {
          float4 acc = {0.f, 0.f, 0.f, 0.f};
          for (int h2 = 0; h2 < 32; ++h2) {   // fixed order
            float4 p = s_pd[h2 * 32 + tid];
            acc.x += p.x; acc.y += p.y; acc.z += p.z; acc.w += p.w;
          }
          *reinterpret_cast<float4*>(dst + oq * 128 + tid * 4) = acc;
        }
        __syncthreads();
      } else if (wg < 160) {
        int rI = wg - 144;  // zero c of inactive rows (new_c = m*c_new)
        if (!((amask >> rI) & 1) && tid < 512) cB[rI * 512 + tid] = 0.f;
      }
    }
    p0 = r0; p1 = r1; p2 = r2; p3 = r3;
    grid.sync();
  }
}

// ============================================================================
extern "C" void kernel_launch(void* const* d_in, const int* in_sizes, int n_in,
                              void* d_out, int out_size, void* d_ws, size_t ws_size,
                              hipStream_t stream) {
  const float* x   = (const float*)d_in[0];
  const float* Wq  = (const float*)d_in[1];
  const float* bq  = (const float*)d_in[2];
  const float* Wk  = (const float*)d_in[3];
  const float* bk  = (const float*)d_in[4];
  const float* Wv  = (const float*)d_in[5];
  const float* bv  = (const float*)d_in[6];
  const float* Wih = (const float*)d_in[7];
  const float* bih = (const float*)d_in[8];
  const float* Whh = (const float*)d_in[9];
  const float* bhh = (const float*)d_in[10];
  const float* Wqg = (const float*)d_in[11];
  const float* Wkg = (const float*)d_in[12];
  const float* Wvg = (const float*)d_in[13];
  float* wsf = (float*)d_ws;
  float* out0 = (float*)d_out;
  float* out1 = out0 + (size_t)T_ * M_ * H_;

  hipLaunchKernelGGL(keyval_kernel, dim3(1536), dim3(256), 0, stream,
                     x, Wk, Wv, bk, bv, wsf);

  void* kargs[] = {(void*)&Wq, (void*)&bq, (void*)&bk, (void*)&bv,
                   (void*)&Wih, (void*)&bih, (void*)&Whh, (void*)&bhh,
                   (void*)&Wqg, (void*)&Wkg, (void*)&Wvg,
                   (void*)&wsf, (void*)&out0, (void*)&out1};
  hipLaunchCooperativeKernel((void*)rim_main, dim3(256), dim3(1024), kargs, 0,
                             stream);
}